// Round 13
// baseline (225.268 us; speedup 1.0000x reference)
//
#include <hip/hip_runtime.h>
#include <math.h>

typedef short bf16x8 __attribute__((ext_vector_type(8)));
typedef float f32x4 __attribute__((ext_vector_type(4)));
typedef unsigned short u16;
typedef unsigned int u32;

#define DEVFN static __device__ __forceinline__

DEVFN u16 f2bf(float f) {
  union { float f; unsigned u; } v; v.f = f;
  return (u16)((v.u + 0x7FFFu + ((v.u >> 16) & 1u)) >> 16);
}

DEVFN float bf2f(u16 u) {
  union { unsigned u; float f; } v; v.u = ((unsigned)u) << 16;
  return v.f;
}

DEVFN void gload16(const void* g, void* l) {
  __builtin_amdgcn_global_load_lds(
      (const __attribute__((address_space(1))) void*)g,
      (__attribute__((address_space(3))) void*)l, 16, 0, 0);
}

// sigmoid-form GELU x*sigmoid(1.702x): output-level error <0.01 (threshold 0.109)
DEVFN float gelu_fast(float x) {
  float e = __expf(-1.702f * x);
  return x * __builtin_amdgcn_rcpf(1.0f + e);
}

// ---------------- constants ----------------
#define TT 100352          // B*D*H*W tokens
#define BWIN 1024          // total windows (B * 256)

// ---------------- weight fp32 -> bf16 (all four in one launch) ----------------
__global__ void convert4_kernel(const float* __restrict__ a, const float* __restrict__ b,
                                const float* __restrict__ c, const float* __restrict__ d,
                                u16* __restrict__ oa, u16* __restrict__ ob,
                                u16* __restrict__ oc, u16* __restrict__ od) {
  int i = blockIdx.x * 256 + threadIdx.x;
  const float* s; u16* o; int off;
  if (i < 49152)       { s = a; o = oa; off = i; }
  else if (i < 65536)  { s = b; o = ob; off = i - 49152; }
  else if (i < 131072) { s = c; o = oc; off = i - 65536; }
  else                 { s = d; o = od; off = i - 131072; }
  o[off] = f2bf(s[off]);
}

// ---- bias+mask in MFMA-fragment layout: bm[pat][h][mt][nt][lane][r] ----
__global__ void biasmask_kernel(const float* __restrict__ rpb, float* __restrict__ bm) {
  int idx = blockIdx.x * 256 + threadIdx.x;   // 8*4*7*7*64 = 100352 total
  int lane = idx & 63;
  int rem = idx >> 6;
  int nt = rem % 7;  rem /= 7;
  int mt = rem % 7;  rem /= 7;
  int h = rem & 3;
  int pat = rem >> 2;
  int dB = (pat >> 2) & 1, hB = (pat >> 1) & 1, wB = pat & 1;
  int jc = nt * 16 + (lane & 15);
  f32x4 out;
  #pragma unroll
  for (int r = 0; r < 4; ++r) {
    int ic = mt * 16 + (lane >> 4) * 4 + r;
    float v;
    if (jc > 97) v = -30000.f;
    else if (ic > 97) v = 0.f;
    else {
      int di = ic / 49, ri = ic % 49, hi = ri / 7, wi = ri % 7;
      int dj = jc / 49, rj = jc % 49, hj = rj / 7, wj = rj % 7;
      int tidx = (di - dj + 1) * 169 + (hi - hj + 6) * 13 + (wi - wj + 6);
      v = rpb[tidx * 4 + h];
      int ridi = (dB ? (di == 0 ? 1 : 2) * 9 : 0) + (hB ? (hi < 4 ? 1 : 2) * 3 : 0)
               + (wB ? (wi < 4 ? 1 : 2) : 0);
      int ridj = (dB ? (dj == 0 ? 1 : 2) * 9 : 0) + (hB ? (hj < 4 ? 1 : 2) * 3 : 0)
               + (wB ? (wj < 4 ? 1 : 2) : 0);
      if (ridi != ridj) v -= 100.f;
    }
    out[r] = v;
  }
  *(f32x4*)(bm + (size_t)idx * 4) = out;
}

// ---------------- LayerNorm 1 (fused shift+window-partition gather) ----------------
__global__ __launch_bounds__(256) void ln_kernel(const float* __restrict__ x,
    const float* __restrict__ w, const float* __restrict__ bterm, u16* __restrict__ out)
{
  int gw = blockIdx.x * 4 + (threadIdx.x >> 6);
  int lane = threadIdx.x & 63;
  int b_ = gw / 98, n = gw % 98;
  int bb = b_ >> 8, widx = b_ & 255;
  int dw = widx >> 6, hw = (widx >> 3) & 7, ww = widx & 7;
  int dd = n / 49, rr = n % 49, hh = rr / 7, wn = rr % 7;
  int d = (dw * 2 + dd + 1) & 7;
  int h = hw * 7 + hh + 3; if (h >= 56) h -= 56;
  int wq = ww * 7 + wn + 3; if (wq >= 56) wq -= 56;
  size_t src = ((size_t)(((bb * 8 + d) * 56 + h) * 56 + wq)) * 128;
  float2 v = *(const float2*)(x + src + lane * 2);
  float s = v.x + v.y, q = v.x * v.x + v.y * v.y;
  #pragma unroll
  for (int m = 1; m < 64; m <<= 1) { s += __shfl_xor(s, m, 64); q += __shfl_xor(q, m, 64); }
  float mu = s * (1.0f / 128.0f);
  float var = q * (1.0f / 128.0f) - mu * mu;
  float rstd = rsqrtf(var + 1e-5f);
  int c = lane * 2;
  float y0 = (v.x - mu) * rstd * w[c] + bterm[c];
  float y1 = (v.y - mu) * rstd * w[c + 1] + bterm[c + 1];
  ushort2 o; o.x = f2bf(y0); o.y = f2bf(y1);
  *(ushort2*)(out + (size_t)gw * 128 + c) = o;
}

// ---------------- qkv GEMM (r9-proven split form) ----------------
__global__ __launch_bounds__(256) void qkvgemm_kernel(
    const u16* __restrict__ A, const u16* __restrict__ Bw,
    const float* __restrict__ bias, u16* __restrict__ outp)
{
  __shared__ u16 smem[16384];           // As[128][64] @0, Bs[128][64] @8192; epilogue reuses 32KB
  u16* As = smem;
  u16* Bs = smem + 8192;
  const int m0 = blockIdx.x * 128, n0 = blockIdx.y * 128;
  const int t = threadIdx.x;
  const int wid = t >> 6, lane = t & 63;
  const int wr = wid >> 1, wc = wid & 1;
  const int l15 = lane & 15, lhi = lane >> 4;
  const int srow = lane >> 3;
  const int sslot = lane & 7;
  const int gcol = ((sslot ^ srow) << 3);
  f32x4 acc[4][4] = {};
  for (int k0 = 0; k0 < 128; k0 += 64) {
    #pragma unroll
    for (int it = 0; it < 4; ++it) {
      const int rbase = it * 32 + wid * 8;
      const int row = rbase + srow;
      gload16(A + (size_t)(m0 + row) * 128 + k0 + gcol, As + rbase * 64);
      gload16(Bw + (size_t)(n0 + row) * 128 + k0 + gcol, Bs + rbase * 64);
    }
    __syncthreads();
    #pragma unroll
    for (int kk = 0; kk < 64; kk += 32) {
      bf16x8 af[4], bfr[4];
      const int csw = (kk + lhi * 8) ^ ((l15 & 7) << 3);
      #pragma unroll
      for (int mi = 0; mi < 4; ++mi) af[mi] = *(const bf16x8*)(As + (wr * 64 + mi * 16 + l15) * 64 + csw);
      #pragma unroll
      for (int ni = 0; ni < 4; ++ni) bfr[ni] = *(const bf16x8*)(Bs + (wc * 64 + ni * 16 + l15) * 64 + csw);
      #pragma unroll
      for (int mi = 0; mi < 4; ++mi)
        #pragma unroll
        for (int ni = 0; ni < 4; ++ni)
          acc[mi][ni] = __builtin_amdgcn_mfma_f32_16x16x32_bf16(af[mi], bfr[ni], acc[mi][ni], 0, 0, 0);
    }
    __syncthreads();
  }
  const float smul = (n0 == 0) ? 0.17677669529663689f : 1.0f;
  #pragma unroll
  for (int mi = 0; mi < 4; ++mi)
    #pragma unroll
    for (int ni = 0; ni < 4; ++ni) {
      int col = wc * 64 + ni * 16 + l15;
      float bcol = bias[n0 + col];
      #pragma unroll
      for (int r = 0; r < 4; ++r) {
        int row = wr * 64 + mi * 16 + lhi * 4 + r;
        float v = (acc[mi][ni][r] + bcol) * smul;
        smem[row * 128 + (((col >> 3) ^ (row & 7)) << 3) + (col & 7)] = f2bf(v);
      }
    }
  __syncthreads();
  const int rsub = t >> 4, sl = t & 15;
  #pragma unroll
  for (int j = 0; j < 8; ++j) {
    int row = j * 16 + rsub;
    int4 val = *(const int4*)(smem + row * 128 + ((sl ^ (row & 7)) << 3));
    *(int4*)(outp + (size_t)(m0 + row) * 384 + n0 + sl * 8) = val;
  }
}

// ---------------- proj GEMM + residual + LN2 (x2 bf16, h1 bf16) ----------------
__global__ __launch_bounds__(256) void proj_kernel(
    const u16* __restrict__ A, const u16* __restrict__ Bw,
    const float* __restrict__ bias, const float* __restrict__ res,
    u16* __restrict__ x2out, const float* __restrict__ n2w,
    const float* __restrict__ n2b, u16* __restrict__ h1out)
{
  __shared__ u16 smem[17664];           // As[128][64] @0, Bs @8192; epilogue Pk[64][138] fp32
  u16* As = smem;
  u16* Bs = smem + 8192;
  const int m0 = blockIdx.x * 128;
  const int t = threadIdx.x;
  const int wid = t >> 6, lane = t & 63;
  const int wr = wid >> 1, wc = wid & 1;
  const int l15 = lane & 15, lhi = lane >> 4;
  const int srow = lane >> 3;
  const int sslot = lane & 7;
  const int gcol = ((sslot ^ srow) << 3);
  f32x4 acc[4][4] = {};
  for (int k0 = 0; k0 < 128; k0 += 64) {
    #pragma unroll
    for (int it = 0; it < 4; ++it) {
      const int rbase = it * 32 + wid * 8;
      const int row = rbase + srow;
      gload16(A + (size_t)(m0 + row) * 128 + k0 + gcol, As + rbase * 64);
      gload16(Bw + (size_t)row * 128 + k0 + gcol, Bs + rbase * 64);
    }
    __syncthreads();
    #pragma unroll
    for (int kk = 0; kk < 64; kk += 32) {
      bf16x8 af[4], bfr[4];
      const int csw = (kk + lhi * 8) ^ ((l15 & 7) << 3);
      #pragma unroll
      for (int mi = 0; mi < 4; ++mi) af[mi] = *(const bf16x8*)(As + (wr * 64 + mi * 16 + l15) * 64 + csw);
      #pragma unroll
      for (int ni = 0; ni < 4; ++ni) bfr[ni] = *(const bf16x8*)(Bs + (wc * 64 + ni * 16 + l15) * 64 + csw);
      #pragma unroll
      for (int mi = 0; mi < 4; ++mi)
        #pragma unroll
        for (int ni = 0; ni < 4; ++ni)
          acc[mi][ni] = __builtin_amdgcn_mfma_f32_16x16x32_bf16(af[mi], bfr[ni], acc[mi][ni], 0, 0, 0);
    }
    __syncthreads();
  }
  float* Pk = (float*)smem;            // [64][138]
  #pragma unroll
  for (int half = 0; half < 2; ++half) {
    if (wr == half) {
      #pragma unroll
      for (int ni = 0; ni < 4; ++ni) {
        int col = wc * 64 + ni * 16 + l15;
        float bcol = bias[col];
        #pragma unroll
        for (int mi = 0; mi < 4; ++mi)
          #pragma unroll
          for (int r = 0; r < 4; ++r)
            Pk[(mi * 16 + lhi * 4 + r) * 138 + col] = acc[mi][ni][r] + bcol;
      }
    }
    __syncthreads();
    {
      int rowl = t >> 2, q = t & 3;
      int grow = m0 + half * 64 + rowl;
      int b_ = grow / 98, n = grow % 98;
      int bb = b_ >> 8, widx = b_ & 255;
      int dw = widx >> 6, hw = (widx >> 3) & 7, ww = widx & 7;
      int dd = n / 49, rr = n % 49, hh = rr / 7, wn = rr % 7;
      int d = (dw * 2 + dd + 1) & 7;
      int hq = hw * 7 + hh + 3; if (hq >= 56) hq -= 56;
      int wq = ww * 7 + wn + 3; if (wq >= 56) wq -= 56;
      size_t dbase = ((size_t)(((bb * 8 + d) * 56 + hq) * 56 + wq)) * 128;
      f32x4 vals[8];
      float s = 0.f, sq = 0.f;
      #pragma unroll
      for (int j = 0; j < 8; ++j) {                 // col = j*16 + q*4 (conflict-free)
        int col = j * 16 + q * 4;
        f32x4 pv = *(const f32x4*)(Pk + rowl * 138 + col);
        f32x4 rv = *(const f32x4*)(res + dbase + col);
        f32x4 v = pv + rv;
        vals[j] = v;
        s += v[0] + v[1] + v[2] + v[3];
        sq += v[0]*v[0] + v[1]*v[1] + v[2]*v[2] + v[3]*v[3];
      }
      s += __shfl_xor(s, 1, 64);  sq += __shfl_xor(sq, 1, 64);
      s += __shfl_xor(s, 2, 64);  sq += __shfl_xor(sq, 2, 64);
      float mu = s * (1.0f / 128.0f);
      float var = sq * (1.0f / 128.0f) - mu * mu;
      float rstd = rsqrtf(var + 1e-5f);
      #pragma unroll
      for (int j = 0; j < 8; ++j) {
        int col = j * 16 + q * 4;
        f32x4 wv = *(const f32x4*)(n2w + col);
        f32x4 bv = *(const f32x4*)(n2b + col);
        u16 xb[4], hb[4];
        #pragma unroll
        for (int e = 0; e < 4; ++e) {
          xb[e] = f2bf(vals[j][e]);
          hb[e] = f2bf((vals[j][e] - mu) * rstd * wv[e] + bv[e]);
        }
        *(int2*)(x2out + dbase + col) = *(const int2*)xb;
        *(int2*)(h1out + dbase + col) = *(const int2*)hb;
      }
    }
    __syncthreads();
  }
}

// ---------------- fused MLP v7: v5 schedule, Hs ELIMINATED via swapped MFMA ----------------
// H computed transposed: accHT = mfma(W1frag, areg) -> lane holds H[tok=l15][hid=lhi*4+r].
// O-MFMA A-fragments built in-register via 8 __shfl + 4 selects each (no LDS round trip).
// LDS 50KB -> 3 blocks/CU; W1 single-buffered, W2 double-buffered (v5-proven schedule).
__global__ __launch_bounds__(256, 3) void mlp_kernel(
    const u16* __restrict__ A, const u16* __restrict__ W1, const float* __restrict__ b1,
    const u16* __restrict__ W2, const float* __restrict__ b2,
    const u16* __restrict__ res, float* __restrict__ outp)
{
  // W1c[64][128] @0 (16KB) | W2c[2][128][64] @8192 elems (32KB) | b1s @24576 elems (2KB)
  __shared__ u16 smem[25600];
  u16* W1c = smem;
  u16* W2c = smem + 8192;
  float* b1s = (float*)(smem + 24576);
  float* Pk = (float*)smem;              // [64][132] fp32 epilogue repack (33.8KB < 48KB)
  const int m0 = blockIdx.x * 128;
  const int t = threadIdx.x, wid = t >> 6, lane = t & 63;
  const int l15 = lane & 15, lhi = lane >> 4;
  const int srow4 = lane >> 4, sslot16 = lane & 15;
  const int srow8 = lane >> 3, sslot8 = lane & 7;
  const int src0 = ((lane & 16) << 1) + l15;   // shuffle sources for H-transpose
  const int src1 = src0 + 16;
  const bool hiSel = (lane & 32) != 0;

  #pragma unroll
  for (int it = 0; it < 4; ++it) {
    int rb1 = it * 16 + wid * 4, r1 = rb1 + srow4;
    gload16(W1 + (size_t)r1 * 128 + ((sslot16 ^ (r1 & 7)) << 3), W1c + rb1 * 128);
    int rb2 = it * 32 + wid * 8, r2 = rb2 + srow8;
    gload16(W2 + (size_t)r2 * 512 + ((sslot8 ^ (r2 & 7)) << 3), W2c + rb2 * 64);
  }
  if (t < 128) *(f32x4*)(b1s + t * 4) = *(const f32x4*)(b1 + t * 4);
  bf16x8 areg[2][4];
  #pragma unroll
  for (int tt = 0; tt < 2; ++tt)
    #pragma unroll
    for (int kg = 0; kg < 4; ++kg)
      areg[tt][kg] = *(const bf16x8*)(A + (size_t)(m0 + wid * 32 + tt * 16 + l15) * 128 + kg * 32 + lhi * 8);

  f32x4 accO[2][8] = {};
  __syncthreads();
  for (int hc = 0; hc < 8; ++hc) {
    const int cur = (hc & 1) * 8192;
    if (hc < 7) {                                    // prefetch next W2 chunk (drains at MID barrier)
      const int nxt = ((hc + 1) & 1) * 8192;
      #pragma unroll
      for (int it = 0; it < 4; ++it) {
        int rb2 = it * 32 + wid * 8, r2 = rb2 + srow8;
        gload16(W2 + (size_t)r2 * 512 + (hc + 1) * 64 + ((sslot8 ^ (r2 & 7)) << 3),
                W2c + nxt + rb2 * 64);
      }
    }
    // ---- swapped H-MFMA: accHT[ht][tt], lane holds H[tok=tt*16+l15][hid=ht*16+lhi*4+r] ----
    f32x4 accHT[4][2] = {};
    #pragma unroll
    for (int kg = 0; kg < 4; ++kg) {
      bf16x8 bw[4];
      #pragma unroll
      for (int ht = 0; ht < 4; ++ht) {
        int row = ht * 16 + l15;
        bw[ht] = *(const bf16x8*)(W1c + row * 128 + (((kg * 4 + lhi) ^ (row & 7)) << 3));
      }
      #pragma unroll
      for (int ht = 0; ht < 4; ++ht)
        #pragma unroll
        for (int tt = 0; tt < 2; ++tt)
          accHT[ht][tt] = __builtin_amdgcn_mfma_f32_16x16x32_bf16(bw[ht], areg[tt][kg], accHT[ht][tt], 0, 0, 0);
    }
    // ---- bias + GELU + pack to bf16 pairs (registers only) ----
    u32 h2x[4][2], h2y[4][2];
    #pragma unroll
    for (int ht = 0; ht < 4; ++ht) {
      f32x4 bbv = *(const f32x4*)(b1s + hc * 64 + ht * 16 + (lhi << 2));
      #pragma unroll
      for (int tt = 0; tt < 2; ++tt) {
        float g0 = gelu_fast(accHT[ht][tt][0] + bbv[0]);
        float g1 = gelu_fast(accHT[ht][tt][1] + bbv[1]);
        float g2 = gelu_fast(accHT[ht][tt][2] + bbv[2]);
        float g3 = gelu_fast(accHT[ht][tt][3] + bbv[3]);
        h2x[ht][tt] = (u32)f2bf(g0) | ((u32)f2bf(g1) << 16);
        h2y[ht][tt] = (u32)f2bf(g2) | ((u32)f2bf(g3) << 16);
      }
    }
    __syncthreads();                // MID: W1c readers done; W2[hc+1] drained
    if (hc < 7) {                   // stage next W1 chunk (drains at END barrier, under O-MFMA)
      #pragma unroll
      for (int it = 0; it < 4; ++it) {
        int rb1 = it * 16 + wid * 4, r1 = rb1 + srow4;
        gload16(W1 + (size_t)((hc + 1) * 64 + r1) * 128 + ((sslot16 ^ (r1 & 7)) << 3),
                W1c + rb1 * 128);
      }
    }
    // ---- O-MFMA: ah built via shuffles; accO += H @ W2c^T ----
    #pragma unroll
    for (int kk = 0; kk < 2; ++kk) {
      bf16x8 bw2[8];
      #pragma unroll
      for (int no = 0; no < 8; ++no) {
        int row = no * 16 + l15;
        bw2[no] = *(const bf16x8*)(W2c + cur + row * 64 + (((kk * 4 + lhi) ^ (row & 7)) << 3));
      }
      #pragma unroll
      for (int tt = 0; tt < 2; ++tt) {
        u32 ax0 = (u32)__shfl((int)h2x[2 * kk][tt], src0, 64);
        u32 bx0 = (u32)__shfl((int)h2x[2 * kk + 1][tt], src0, 64);
        u32 ay0 = (u32)__shfl((int)h2y[2 * kk][tt], src0, 64);
        u32 by0 = (u32)__shfl((int)h2y[2 * kk + 1][tt], src0, 64);
        u32 ax1 = (u32)__shfl((int)h2x[2 * kk][tt], src1, 64);
        u32 bx1 = (u32)__shfl((int)h2x[2 * kk + 1][tt], src1, 64);
        u32 ay1 = (u32)__shfl((int)h2y[2 * kk][tt], src1, 64);
        u32 by1 = (u32)__shfl((int)h2y[2 * kk + 1][tt], src1, 64);
        union { u32 w[4]; bf16x8 v; } U;
        U.w[0] = hiSel ? bx0 : ax0;
        U.w[1] = hiSel ? by0 : ay0;
        U.w[2] = hiSel ? bx1 : ax1;
        U.w[3] = hiSel ? by1 : ay1;
        #pragma unroll
        for (int no = 0; no < 8; ++no)
          accO[tt][no] = __builtin_amdgcn_mfma_f32_16x16x32_bf16(U.v, bw2[no], accO[tt][no], 0, 0, 0);
      }
    }
    __syncthreads();                // END: W2c[cur] free; W1[hc+1] drained
  }
  // ---- epilogue: two halves of 64 tokens through fp32 LDS repack ----
  #pragma unroll
  for (int half = 0; half < 2; ++half) {
    if ((wid >> 1) == half) {
      #pragma unroll
      for (int no = 0; no < 8; ++no) {
        int col = no * 16 + l15;
        float bv = b2[col];
        #pragma unroll
        for (int tt = 0; tt < 2; ++tt)
          #pragma unroll
          for (int r = 0; r < 4; ++r) {
            int tokl = (wid & 1) * 32 + tt * 16 + lhi * 4 + r;
            Pk[tokl * 132 + col] = accO[tt][no][r] + bv;
          }
      }
    }
    __syncthreads();
    #pragma unroll
    for (int p = 0; p < 8; ++p) {
      int idx = p * 256 + t;
      int row = idx >> 5, c = (idx & 31) * 4;
      size_t gtok = (size_t)(m0 + half * 64 + row);
      f32x4 v = *(const f32x4*)(Pk + row * 132 + c);
      short4 rb = *(const short4*)(res + gtok * 128 + c);
      f32x4 rv;
      rv[0] = bf2f((u16)rb.x); rv[1] = bf2f((u16)rb.y);
      rv[2] = bf2f((u16)rb.z); rv[3] = bf2f((u16)rb.w);
      *(f32x4*)(outp + gtok * 128 + c) = v + rv;
    }
    __syncthreads();
  }
}

// ---------------- windowed attention v3: one wave per (window, head) ----------------
__global__ __launch_bounds__(64) void attn_kernel(
    const u16* __restrict__ qkv, const float* __restrict__ biasmask,
    u16* __restrict__ out_win)
{
  __shared__ u16 vT[32][136];
  __shared__ u16 P[16][136];
  const int bid = blockIdx.x;
  const int w = bid >> 2, h = bid & 3;
  const int lane = threadIdx.x;
  const int l15 = lane & 15, lhi = lane >> 4;
  const int widx = w & 255;
  const int dw = widx >> 6, hw = (widx >> 3) & 7, ww = widx & 7;
  const int pat = ((dw == 3) ? 4 : 0) | ((hw == 7) ? 2 : 0) | ((ww == 7) ? 1 : 0);
  const float* bmh = biasmask + (size_t)(pat * 4 + h) * (49 * 256);

  for (int f = lane; f < 160; f += 64) {
    int d = f / 5, c = 96 + (f % 5) * 8;
    *(int4*)&vT[d][c] = (int4){0, 0, 0, 0};
  }
  if (lane < 48) {
    int r = lane / 3, c = 112 + (lane % 3) * 8;
    *(int4*)&P[r][c] = (int4){0, 0, 0, 0};
  }
  const size_t base = (size_t)w * 98 * 384;
  for (int f = lane; f < 392; f += 64) {
    int n = f >> 2, c = (f & 3) * 8;
    int4 v = *(const int4*)(qkv + base + (size_t)n * 384 + 256 + h * 32 + c);
    const u16* pv = (const u16*)&v;
    #pragma unroll
    for (int j = 0; j < 8; ++j) vT[c + j][n] = pv[j];
  }
  const size_t obase = (size_t)w * 98 * 128;
  for (int mt = 0; mt < 7; ++mt) {
    int qn = mt * 16 + l15; if (qn > 97) qn = 97;
    bf16x8 aq = *(const bf16x8*)(qkv + base + (size_t)qn * 384 + h * 32 + lhi * 8);
    f32x4 sf[7];
    #pragma unroll
    for (int nt = 0; nt < 7; ++nt) {
      int kn = nt * 16 + l15; if (kn > 97) kn = 97;
      bf16x8 bk = *(const bf16x8*)(qkv + base + (size_t)kn * 384 + 128 + h * 32 + lhi * 8);
      f32x4 z = {0.f, 0.f, 0.f, 0.f};
      sf[nt] = __builtin_amdgcn_mfma_f32_16x16x32_bf16(aq, bk, z, 0, 0, 0);
    }
    float mx[4] = {-1e30f, -1e30f, -1e30f, -1e30f};
    #pragma unroll
    for (int nt = 0; nt < 7; ++nt) {
      f32x4 bm = *(const f32x4*)(bmh + (mt * 7 + nt) * 256 + lane * 4);
      #pragma unroll
      for (int r = 0; r < 4; ++r) {
        float s = sf[nt][r] + bm[r];
        sf[nt][r] = s;
        mx[r] = fmaxf(mx[r], s);
      }
    }
    #pragma unroll
    for (int m = 1; m < 16; m <<= 1)
      #pragma unroll
      for (int r = 0; r < 4; ++r) mx[r] = fmaxf(mx[r], __shfl_xor(mx[r], m, 64));
    float sm[4] = {0.f, 0.f, 0.f, 0.f};
    #pragma unroll
    for (int nt = 0; nt < 7; ++nt)
      #pragma unroll
      for (int r = 0; r < 4; ++r) {
        float p = __expf(sf[nt][r] - mx[r]);
        sf[nt][r] = p;
        sm[r] += p;
      }
    #pragma unroll
    for (int m = 1; m < 16; m <<= 1)
      #pragma unroll
      for (int r = 0; r < 4; ++r) sm[r] += __shfl_xor(sm[r], m, 64);
    float inv[4];
    #pragma unroll
    for (int r = 0; r < 4; ++r) inv[r] = 1.0f / sm[r];
    #pragma unroll
    for (int nt = 0; nt < 7; ++nt)
      #pragma unroll
      for (int r = 0; r < 4; ++r)
        P[lhi * 4 + r][nt * 16 + l15] = f2bf(sf[nt][r] * inv[r]);
    f32x4 o0 = {}, o1 = {};
    #pragma unroll
    for (int ks = 0; ks < 4; ++ks) {
      bf16x8 ap  = *(const bf16x8*)(&P[l15][ks * 32 + lhi * 8]);
      bf16x8 bv0 = *(const bf16x8*)(&vT[l15][ks * 32 + lhi * 8]);
      bf16x8 bv1 = *(const bf16x8*)(&vT[16 + l15][ks * 32 + lhi * 8]);
      o0 = __builtin_amdgcn_mfma_f32_16x16x32_bf16(ap, bv0, o0, 0, 0, 0);
      o1 = __builtin_amdgcn_mfma_f32_16x16x32_bf16(ap, bv1, o1, 0, 0, 0);
    }
    int irow0 = mt * 16 + lhi * 4;
    #pragma unroll
    for (int r = 0; r < 4; ++r) {
      if (irow0 + r < 98) {
        size_t orow = obase + (size_t)(irow0 + r) * 128 + h * 32;
        out_win[orow + l15] = f2bf(o0[r]);
        out_win[orow + 16 + l15] = f2bf(o1[r]);
      }
    }
  }
}

// ---------------- launcher ----------------
extern "C" void kernel_launch(void* const* d_in, const int* in_sizes, int n_in,
                              void* d_out, int out_size, void* d_ws, size_t ws_size,
                              hipStream_t stream)
{
  const float* x      = (const float*)d_in[0];
  const float* n1w    = (const float*)d_in[1];
  const float* n1b    = (const float*)d_in[2];
  const float* qkv_w  = (const float*)d_in[3];
  const float* qkv_b  = (const float*)d_in[4];
  const float* rpb    = (const float*)d_in[5];
  const float* proj_w = (const float*)d_in[6];
  const float* proj_b = (const float*)d_in[7];
  const float* n2w    = (const float*)d_in[8];
  const float* n2b    = (const float*)d_in[9];
  const float* fc1_w  = (const float*)d_in[10];
  const float* fc1_b  = (const float*)d_in[11];
  const float* fc2_w  = (const float*)d_in[12];
  const float* fc2_b  = (const float*)d_in[13];

  char* p = (char*)d_ws;
  size_t off = 0;
  auto alloc = [&](size_t bytes) { void* r = p + off; off = (off + bytes + 255) & ~(size_t)255; return r; };
  u16*   qkvw_b    = (u16*)alloc(49152 * 2);
  u16*   projw_b   = (u16*)alloc(16384 * 2);
  u16*   fc1w_b    = (u16*)alloc(65536 * 2);
  u16*   fc2w_b    = (u16*)alloc(65536 * 2);
  float* biasmask  = (float*)alloc(8 * 4 * 49 * 256 * 4);
  u16*   y_win     = (u16*)alloc((size_t)TT * 128 * 2);   // LN1 out, then attn out
  u16*   x2        = (u16*)alloc((size_t)TT * 128 * 2);   // bf16 residual
  u16*   h1        = (u16*)alloc((size_t)TT * 128 * 2);
  u16*   big       = (u16*)alloc((size_t)TT * 384 * 2);   // qkv
  if (off > ws_size) return;

  convert4_kernel<<<768, 256, 0, stream>>>(qkv_w, proj_w, fc1_w, fc2_w,
                                           qkvw_b, projw_b, fc1w_b, fc2w_b);
  biasmask_kernel<<<392, 256, 0, stream>>>(rpb, biasmask);
  ln_kernel<<<TT / 4, 256, 0, stream>>>(x, n1w, n1b, y_win);
  qkvgemm_kernel<<<dim3(TT / 128, 3), 256, 0, stream>>>(y_win, qkvw_b, qkv_b, big);
  attn_kernel<<<BWIN * 4, 64, 0, stream>>>(big, biasmask, y_win);
  proj_kernel<<<TT / 128, 256, 0, stream>>>(y_win, projw_b, proj_b, x, x2, n2w, n2b, h1);
  mlp_kernel<<<TT / 128, 256, 0, stream>>>(h1, fc1w_b, fc1_b, fc2w_b, fc2_b, x2, (float*)d_out);
}

// Round 14
// 189.644 us; speedup vs baseline: 1.1878x; 1.1878x over previous
//
#include <hip/hip_runtime.h>
#include <math.h>

typedef short bf16x8 __attribute__((ext_vector_type(8)));
typedef float f32x4 __attribute__((ext_vector_type(4)));
typedef unsigned short u16;
typedef unsigned int u32;

#define DEVFN static __device__ __forceinline__

DEVFN u16 f2bf(float f) {
  union { float f; unsigned u; } v; v.f = f;
  return (u16)((v.u + 0x7FFFu + ((v.u >> 16) & 1u)) >> 16);
}

DEVFN float bf2f(u16 u) {
  union { unsigned u; float f; } v; v.u = ((unsigned)u) << 16;
  return v.f;
}

DEVFN void gload16(const void* g, void* l) {
  __builtin_amdgcn_global_load_lds(
      (const __attribute__((address_space(1))) void*)g,
      (__attribute__((address_space(3))) void*)l, 16, 0, 0);
}

// sigmoid-form GELU x*sigmoid(1.702x): output-level error <0.01 (threshold 0.109)
DEVFN float gelu_fast(float x) {
  float e = __expf(-1.702f * x);
  return x * __builtin_amdgcn_rcpf(1.0f + e);
}

// ---------------- constants ----------------
#define TT 100352          // B*D*H*W tokens
#define BWIN 1024          // total windows (B * 256)

// ---------------- weight fp32 -> bf16 (all four in one launch) ----------------
__global__ void convert4_kernel(const float* __restrict__ a, const float* __restrict__ b,
                                const float* __restrict__ c, const float* __restrict__ d,
                                u16* __restrict__ oa, u16* __restrict__ ob,
                                u16* __restrict__ oc, u16* __restrict__ od) {
  int i = blockIdx.x * 256 + threadIdx.x;
  const float* s; u16* o; int off;
  if (i < 49152)       { s = a; o = oa; off = i; }
  else if (i < 65536)  { s = b; o = ob; off = i - 49152; }
  else if (i < 131072) { s = c; o = oc; off = i - 65536; }
  else                 { s = d; o = od; off = i - 131072; }
  o[off] = f2bf(s[off]);
}

// ---- bias+mask in MFMA-fragment layout: bm[pat][h][mt][nt][lane][r] ----
__global__ void biasmask_kernel(const float* __restrict__ rpb, float* __restrict__ bm) {
  int idx = blockIdx.x * 256 + threadIdx.x;   // 8*4*7*7*64 = 100352 total
  int lane = idx & 63;
  int rem = idx >> 6;
  int nt = rem % 7;  rem /= 7;
  int mt = rem % 7;  rem /= 7;
  int h = rem & 3;
  int pat = rem >> 2;
  int dB = (pat >> 2) & 1, hB = (pat >> 1) & 1, wB = pat & 1;
  int jc = nt * 16 + (lane & 15);
  f32x4 out;
  #pragma unroll
  for (int r = 0; r < 4; ++r) {
    int ic = mt * 16 + (lane >> 4) * 4 + r;
    float v;
    if (jc > 97) v = -30000.f;
    else if (ic > 97) v = 0.f;
    else {
      int di = ic / 49, ri = ic % 49, hi = ri / 7, wi = ri % 7;
      int dj = jc / 49, rj = jc % 49, hj = rj / 7, wj = rj % 7;
      int tidx = (di - dj + 1) * 169 + (hi - hj + 6) * 13 + (wi - wj + 6);
      v = rpb[tidx * 4 + h];
      int ridi = (dB ? (di == 0 ? 1 : 2) * 9 : 0) + (hB ? (hi < 4 ? 1 : 2) * 3 : 0)
               + (wB ? (wi < 4 ? 1 : 2) : 0);
      int ridj = (dB ? (dj == 0 ? 1 : 2) * 9 : 0) + (hB ? (hj < 4 ? 1 : 2) * 3 : 0)
               + (wB ? (wj < 4 ? 1 : 2) : 0);
      if (ridi != ridj) v -= 100.f;
    }
    out[r] = v;
  }
  *(f32x4*)(bm + (size_t)idx * 4) = out;
}

// ---------------- LayerNorm 1 (fused shift+window-partition gather) ----------------
__global__ __launch_bounds__(256) void ln_kernel(const float* __restrict__ x,
    const float* __restrict__ w, const float* __restrict__ bterm, u16* __restrict__ out)
{
  int gw = blockIdx.x * 4 + (threadIdx.x >> 6);
  int lane = threadIdx.x & 63;
  int b_ = gw / 98, n = gw % 98;
  int bb = b_ >> 8, widx = b_ & 255;
  int dw = widx >> 6, hw = (widx >> 3) & 7, ww = widx & 7;
  int dd = n / 49, rr = n % 49, hh = rr / 7, wn = rr % 7;
  int d = (dw * 2 + dd + 1) & 7;
  int h = hw * 7 + hh + 3; if (h >= 56) h -= 56;
  int wq = ww * 7 + wn + 3; if (wq >= 56) wq -= 56;
  size_t src = ((size_t)(((bb * 8 + d) * 56 + h) * 56 + wq)) * 128;
  float2 v = *(const float2*)(x + src + lane * 2);
  float s = v.x + v.y, q = v.x * v.x + v.y * v.y;
  #pragma unroll
  for (int m = 1; m < 64; m <<= 1) { s += __shfl_xor(s, m, 64); q += __shfl_xor(q, m, 64); }
  float mu = s * (1.0f / 128.0f);
  float var = q * (1.0f / 128.0f) - mu * mu;
  float rstd = rsqrtf(var + 1e-5f);
  int c = lane * 2;
  float y0 = (v.x - mu) * rstd * w[c] + bterm[c];
  float y1 = (v.y - mu) * rstd * w[c + 1] + bterm[c + 1];
  ushort2 o; o.x = f2bf(y0); o.y = f2bf(y1);
  *(ushort2*)(out + (size_t)gw * 128 + c) = o;
}

// ---------------- qkv GEMM (r9-proven split form) ----------------
__global__ __launch_bounds__(256) void qkvgemm_kernel(
    const u16* __restrict__ A, const u16* __restrict__ Bw,
    const float* __restrict__ bias, u16* __restrict__ outp)
{
  __shared__ u16 smem[16384];           // As[128][64] @0, Bs[128][64] @8192; epilogue reuses 32KB
  u16* As = smem;
  u16* Bs = smem + 8192;
  const int m0 = blockIdx.x * 128, n0 = blockIdx.y * 128;
  const int t = threadIdx.x;
  const int wid = t >> 6, lane = t & 63;
  const int wr = wid >> 1, wc = wid & 1;
  const int l15 = lane & 15, lhi = lane >> 4;
  const int srow = lane >> 3;
  const int sslot = lane & 7;
  const int gcol = ((sslot ^ srow) << 3);
  f32x4 acc[4][4] = {};
  for (int k0 = 0; k0 < 128; k0 += 64) {
    #pragma unroll
    for (int it = 0; it < 4; ++it) {
      const int rbase = it * 32 + wid * 8;
      const int row = rbase + srow;
      gload16(A + (size_t)(m0 + row) * 128 + k0 + gcol, As + rbase * 64);
      gload16(Bw + (size_t)(n0 + row) * 128 + k0 + gcol, Bs + rbase * 64);
    }
    __syncthreads();
    #pragma unroll
    for (int kk = 0; kk < 64; kk += 32) {
      bf16x8 af[4], bfr[4];
      const int csw = (kk + lhi * 8) ^ ((l15 & 7) << 3);
      #pragma unroll
      for (int mi = 0; mi < 4; ++mi) af[mi] = *(const bf16x8*)(As + (wr * 64 + mi * 16 + l15) * 64 + csw);
      #pragma unroll
      for (int ni = 0; ni < 4; ++ni) bfr[ni] = *(const bf16x8*)(Bs + (wc * 64 + ni * 16 + l15) * 64 + csw);
      #pragma unroll
      for (int mi = 0; mi < 4; ++mi)
        #pragma unroll
        for (int ni = 0; ni < 4; ++ni)
          acc[mi][ni] = __builtin_amdgcn_mfma_f32_16x16x32_bf16(af[mi], bfr[ni], acc[mi][ni], 0, 0, 0);
    }
    __syncthreads();
  }
  const float smul = (n0 == 0) ? 0.17677669529663689f : 1.0f;
  #pragma unroll
  for (int mi = 0; mi < 4; ++mi)
    #pragma unroll
    for (int ni = 0; ni < 4; ++ni) {
      int col = wc * 64 + ni * 16 + l15;
      float bcol = bias[n0 + col];
      #pragma unroll
      for (int r = 0; r < 4; ++r) {
        int row = wr * 64 + mi * 16 + lhi * 4 + r;
        float v = (acc[mi][ni][r] + bcol) * smul;
        smem[row * 128 + (((col >> 3) ^ (row & 7)) << 3) + (col & 7)] = f2bf(v);
      }
    }
  __syncthreads();
  const int rsub = t >> 4, sl = t & 15;
  #pragma unroll
  for (int j = 0; j < 8; ++j) {
    int row = j * 16 + rsub;
    int4 val = *(const int4*)(smem + row * 128 + ((sl ^ (row & 7)) << 3));
    *(int4*)(outp + (size_t)(m0 + row) * 384 + n0 + sl * 8) = val;
  }
}

// ---------------- proj GEMM + residual -> x2 bf16 (window-reverse scatter) ----------------
__global__ __launch_bounds__(256) void proj_kernel(
    const u16* __restrict__ A, const u16* __restrict__ Bw,
    const float* __restrict__ bias, const float* __restrict__ res,
    u16* __restrict__ x2out)
{
  __shared__ u16 smem[17664];           // As[128][64] @0, Bs @8192; epilogue Pk[64][138] fp32
  u16* As = smem;
  u16* Bs = smem + 8192;
  const int m0 = blockIdx.x * 128;
  const int t = threadIdx.x;
  const int wid = t >> 6, lane = t & 63;
  const int wr = wid >> 1, wc = wid & 1;
  const int l15 = lane & 15, lhi = lane >> 4;
  const int srow = lane >> 3;
  const int sslot = lane & 7;
  const int gcol = ((sslot ^ srow) << 3);
  f32x4 acc[4][4] = {};
  for (int k0 = 0; k0 < 128; k0 += 64) {
    #pragma unroll
    for (int it = 0; it < 4; ++it) {
      const int rbase = it * 32 + wid * 8;
      const int row = rbase + srow;
      gload16(A + (size_t)(m0 + row) * 128 + k0 + gcol, As + rbase * 64);
      gload16(Bw + (size_t)row * 128 + k0 + gcol, Bs + rbase * 64);
    }
    __syncthreads();
    #pragma unroll
    for (int kk = 0; kk < 64; kk += 32) {
      bf16x8 af[4], bfr[4];
      const int csw = (kk + lhi * 8) ^ ((l15 & 7) << 3);
      #pragma unroll
      for (int mi = 0; mi < 4; ++mi) af[mi] = *(const bf16x8*)(As + (wr * 64 + mi * 16 + l15) * 64 + csw);
      #pragma unroll
      for (int ni = 0; ni < 4; ++ni) bfr[ni] = *(const bf16x8*)(Bs + (wc * 64 + ni * 16 + l15) * 64 + csw);
      #pragma unroll
      for (int mi = 0; mi < 4; ++mi)
        #pragma unroll
        for (int ni = 0; ni < 4; ++ni)
          acc[mi][ni] = __builtin_amdgcn_mfma_f32_16x16x32_bf16(af[mi], bfr[ni], acc[mi][ni], 0, 0, 0);
    }
    __syncthreads();
  }
  float* Pk = (float*)smem;            // [64][138]
  #pragma unroll
  for (int half = 0; half < 2; ++half) {
    if (wr == half) {
      #pragma unroll
      for (int ni = 0; ni < 4; ++ni) {
        int col = wc * 64 + ni * 16 + l15;
        float bcol = bias[col];
        #pragma unroll
        for (int mi = 0; mi < 4; ++mi)
          #pragma unroll
          for (int r = 0; r < 4; ++r)
            Pk[(mi * 16 + lhi * 4 + r) * 138 + col] = acc[mi][ni][r] + bcol;
      }
    }
    __syncthreads();
    {
      int rowl = t >> 2, q = t & 3;
      int grow = m0 + half * 64 + rowl;
      int b_ = grow / 98, n = grow % 98;
      int bb = b_ >> 8, widx = b_ & 255;
      int dw = widx >> 6, hw = (widx >> 3) & 7, ww = widx & 7;
      int dd = n / 49, rr = n % 49, hh = rr / 7, wn = rr % 7;
      int d = (dw * 2 + dd + 1) & 7;
      int hq = hw * 7 + hh + 3; if (hq >= 56) hq -= 56;
      int wq = ww * 7 + wn + 3; if (wq >= 56) wq -= 56;
      size_t dbase = ((size_t)(((bb * 8 + d) * 56 + hq) * 56 + wq)) * 128;
      #pragma unroll
      for (int j = 0; j < 8; ++j) {                 // col = j*16 + q*4 (conflict-free)
        int col = j * 16 + q * 4;
        f32x4 pv = *(const f32x4*)(Pk + rowl * 138 + col);
        f32x4 rv = *(const f32x4*)(res + dbase + col);
        f32x4 v = pv + rv;
        u16 xb[4];
        #pragma unroll
        for (int e = 0; e < 4; ++e) xb[e] = f2bf(v[e]);
        *(int2*)(x2out + dbase + col) = *(const int2*)xb;
      }
    }
    __syncthreads();
  }
}

// ---------------- fused MLP v5 (r7/r11-proven) + INLINE LayerNorm2 ----------------
// A = x2 (bf16). LN2 computed in the prologue: each row's 128 channels live in
// 4 lanes (lhi=0..3, fixed l15) -> 2 shfl_xor reduce, normalize into areg.
__global__ __launch_bounds__(256, 2) void mlp_kernel(
    const u16* __restrict__ x2, const float* __restrict__ n2w, const float* __restrict__ n2b,
    const u16* __restrict__ W1, const float* __restrict__ b1,
    const u16* __restrict__ W2, const float* __restrict__ b2,
    float* __restrict__ outp)
{
  // W1c[64][128] @0 | W2c[2][128][64] @16KB | Hs[4][32][72] @48KB | b1s @66KB  (68KB)
  __shared__ u16 smem[34816];
  u16* W1c = smem;
  u16* W2c = smem + 8192;
  u16* HsA = smem + 24576;
  float* b1s = (float*)(smem + 33792);
  float* Pk = (float*)smem;              // [64][132] fp32 epilogue repack
  const int m0 = blockIdx.x * 128;
  const int t = threadIdx.x, wid = t >> 6, lane = t & 63;
  const int l15 = lane & 15, lhi = lane >> 4;
  const int srow4 = lane >> 4, sslot16 = lane & 15;
  const int srow8 = lane >> 3, sslot8 = lane & 7;
  u16* hs = HsA + wid * 2304;            // wave-private [32][72]

  #pragma unroll
  for (int it = 0; it < 4; ++it) {
    int rb1 = it * 16 + wid * 4, r1 = rb1 + srow4;
    gload16(W1 + (size_t)r1 * 128 + ((sslot16 ^ (r1 & 7)) << 3), W1c + rb1 * 128);
    int rb2 = it * 32 + wid * 8, r2 = rb2 + srow8;
    gload16(W2 + (size_t)r2 * 512 + ((sslot8 ^ (r2 & 7)) << 3), W2c + rb2 * 64);
  }
  if (t < 128) *(f32x4*)(b1s + t * 4) = *(const f32x4*)(b1 + t * 4);

  // ---- A-fragments with inline LN2 ----
  bf16x8 areg[2][4];
  {
    bf16x8 raw[2][4];
    float sum[2] = {0.f, 0.f}, sq[2] = {0.f, 0.f};
    #pragma unroll
    for (int tt = 0; tt < 2; ++tt)
      #pragma unroll
      for (int kg = 0; kg < 4; ++kg) {
        raw[tt][kg] = *(const bf16x8*)(x2 + (size_t)(m0 + wid * 32 + tt * 16 + l15) * 128 + kg * 32 + lhi * 8);
        #pragma unroll
        for (int e = 0; e < 8; ++e) {
          float f = bf2f((u16)raw[tt][kg][e]);
          sum[tt] += f; sq[tt] += f * f;
        }
      }
    #pragma unroll
    for (int tt = 0; tt < 2; ++tt) {
      sum[tt] += __shfl_xor(sum[tt], 16, 64);  sq[tt] += __shfl_xor(sq[tt], 16, 64);
      sum[tt] += __shfl_xor(sum[tt], 32, 64);  sq[tt] += __shfl_xor(sq[tt], 32, 64);
    }
    float mu[2], rstd[2];
    #pragma unroll
    for (int tt = 0; tt < 2; ++tt) {
      mu[tt] = sum[tt] * (1.0f / 128.0f);
      float var = sq[tt] * (1.0f / 128.0f) - mu[tt] * mu[tt];
      rstd[tt] = rsqrtf(var + 1e-5f);
    }
    #pragma unroll
    for (int kg = 0; kg < 4; ++kg) {
      int col = kg * 32 + lhi * 8;
      f32x4 w0 = *(const f32x4*)(n2w + col);
      f32x4 w1 = *(const f32x4*)(n2w + col + 4);
      f32x4 b0 = *(const f32x4*)(n2b + col);
      f32x4 b1v = *(const f32x4*)(n2b + col + 4);
      #pragma unroll
      for (int tt = 0; tt < 2; ++tt) {
        u16 hb[8];
        #pragma unroll
        for (int e = 0; e < 4; ++e) {
          hb[e]     = f2bf((bf2f((u16)raw[tt][kg][e])     - mu[tt]) * rstd[tt] * w0[e] + b0[e]);
          hb[e + 4] = f2bf((bf2f((u16)raw[tt][kg][e + 4]) - mu[tt]) * rstd[tt] * w1[e] + b1v[e]);
        }
        areg[tt][kg] = *(const bf16x8*)hb;
      }
    }
  }

  f32x4 accO[2][8] = {};
  __syncthreads();
  for (int hc = 0; hc < 8; ++hc) {
    const int cur = (hc & 1) * 8192;
    if (hc < 7) {                                    // prefetch next W2 chunk (drains at MID barrier)
      const int nxt = ((hc + 1) & 1) * 8192;
      #pragma unroll
      for (int it = 0; it < 4; ++it) {
        int rb2 = it * 32 + wid * 8, r2 = rb2 + srow8;
        gload16(W2 + (size_t)r2 * 512 + (hc + 1) * 64 + ((sslot8 ^ (r2 & 7)) << 3),
                W2c + nxt + rb2 * 64);
      }
    }
    f32x4 accH[2][4] = {};
    #pragma unroll
    for (int kk = 0; kk < 4; ++kk) {
      bf16x8 bw[4];
      #pragma unroll
      for (int ni = 0; ni < 4; ++ni) {
        int row = ni * 16 + l15;
        bw[ni] = *(const bf16x8*)(W1c + row * 128 + (((kk * 4 + lhi) ^ (row & 7)) << 3));
      }
      #pragma unroll
      for (int mi = 0; mi < 2; ++mi)
        #pragma unroll
        for (int ni = 0; ni < 4; ++ni)
          accH[mi][ni] = __builtin_amdgcn_mfma_f32_16x16x32_bf16(areg[mi][kk], bw[ni], accH[mi][ni], 0, 0, 0);
    }
    #pragma unroll
    for (int mi = 0; mi < 2; ++mi)
      #pragma unroll
      for (int ni = 0; ni < 4; ++ni) {
        float bb = b1s[hc * 64 + ni * 16 + l15];
        #pragma unroll
        for (int r = 0; r < 4; ++r) {
          int tokl = mi * 16 + lhi * 4 + r;
          hs[tokl * 72 + ni * 16 + l15] = f2bf(gelu_fast(accH[mi][ni][r] + bb));
        }
      }
    __syncthreads();                // MID: W1c readers done; W2[hc+1] drained
    if (hc < 7) {                   // stage next W1 chunk (drains at END barrier, under O-MFMA)
      #pragma unroll
      for (int it = 0; it < 4; ++it) {
        int rb1 = it * 16 + wid * 4, r1 = rb1 + srow4;
        gload16(W1 + (size_t)((hc + 1) * 64 + r1) * 128 + ((sslot16 ^ (r1 & 7)) << 3),
                W1c + rb1 * 128);
      }
    }
    #pragma unroll
    for (int kk = 0; kk < 2; ++kk) {
      bf16x8 ah[2], bw2[8];
      #pragma unroll
      for (int mi = 0; mi < 2; ++mi)
        ah[mi] = *(const bf16x8*)(hs + (mi * 16 + l15) * 72 + kk * 32 + lhi * 8);
      #pragma unroll
      for (int ni = 0; ni < 8; ++ni) {
        int row = ni * 16 + l15;
        bw2[ni] = *(const bf16x8*)(W2c + cur + row * 64 + (((kk * 4 + lhi) ^ (row & 7)) << 3));
      }
      #pragma unroll
      for (int mi = 0; mi < 2; ++mi)
        #pragma unroll
        for (int ni = 0; ni < 8; ++ni)
          accO[mi][ni] = __builtin_amdgcn_mfma_f32_16x16x32_bf16(ah[mi], bw2[ni], accO[mi][ni], 0, 0, 0);
    }
    __syncthreads();                // END: Hs+W2c[cur] free; W1[hc+1] drained
  }
  // ---- epilogue: two halves of 64 tokens through fp32 LDS repack ----
  #pragma unroll
  for (int half = 0; half < 2; ++half) {
    if ((wid >> 1) == half) {
      #pragma unroll
      for (int ni = 0; ni < 8; ++ni) {
        int col = ni * 16 + l15;
        float bv = b2[col];
        #pragma unroll
        for (int mi = 0; mi < 2; ++mi)
          #pragma unroll
          for (int r = 0; r < 4; ++r) {
            int tokl = (wid & 1) * 32 + mi * 16 + lhi * 4 + r;
            Pk[tokl * 132 + col] = accO[mi][ni][r] + bv;
          }
      }
    }
    __syncthreads();
    #pragma unroll
    for (int p = 0; p < 8; ++p) {
      int idx = p * 256 + t;
      int row = idx >> 5, c = (idx & 31) * 4;
      size_t gtok = (size_t)(m0 + half * 64 + row);
      f32x4 v = *(const f32x4*)(Pk + row * 132 + c);
      short4 rb = *(const short4*)(x2 + gtok * 128 + c);
      f32x4 rv;
      rv[0] = bf2f((u16)rb.x); rv[1] = bf2f((u16)rb.y);
      rv[2] = bf2f((u16)rb.z); rv[3] = bf2f((u16)rb.w);
      *(f32x4*)(outp + gtok * 128 + c) = v + rv;
    }
    __syncthreads();
  }
}

// ---------------- windowed attention v3: one wave per (window, head) ----------------
__global__ __launch_bounds__(64) void attn_kernel(
    const u16* __restrict__ qkv, const float* __restrict__ biasmask,
    u16* __restrict__ out_win)
{
  __shared__ u16 vT[32][136];
  __shared__ u16 P[16][136];
  const int bid = blockIdx.x;
  const int w = bid >> 2, h = bid & 3;
  const int lane = threadIdx.x;
  const int l15 = lane & 15, lhi = lane >> 4;
  const int widx = w & 255;
  const int dw = widx >> 6, hw = (widx >> 3) & 7, ww = widx & 7;
  const int pat = ((dw == 3) ? 4 : 0) | ((hw == 7) ? 2 : 0) | ((ww == 7) ? 1 : 0);
  const float* bmh = biasmask + (size_t)(pat * 4 + h) * (49 * 256);

  for (int f = lane; f < 160; f += 64) {
    int d = f / 5, c = 96 + (f % 5) * 8;
    *(int4*)&vT[d][c] = (int4){0, 0, 0, 0};
  }
  if (lane < 48) {
    int r = lane / 3, c = 112 + (lane % 3) * 8;
    *(int4*)&P[r][c] = (int4){0, 0, 0, 0};
  }
  const size_t base = (size_t)w * 98 * 384;
  for (int f = lane; f < 392; f += 64) {
    int n = f >> 2, c = (f & 3) * 8;
    int4 v = *(const int4*)(qkv + base + (size_t)n * 384 + 256 + h * 32 + c);
    const u16* pv = (const u16*)&v;
    #pragma unroll
    for (int j = 0; j < 8; ++j) vT[c + j][n] = pv[j];
  }
  const size_t obase = (size_t)w * 98 * 128;
  for (int mt = 0; mt < 7; ++mt) {
    int qn = mt * 16 + l15; if (qn > 97) qn = 97;
    bf16x8 aq = *(const bf16x8*)(qkv + base + (size_t)qn * 384 + h * 32 + lhi * 8);
    f32x4 sf[7];
    #pragma unroll
    for (int nt = 0; nt < 7; ++nt) {
      int kn = nt * 16 + l15; if (kn > 97) kn = 97;
      bf16x8 bk = *(const bf16x8*)(qkv + base + (size_t)kn * 384 + 128 + h * 32 + lhi * 8);
      f32x4 z = {0.f, 0.f, 0.f, 0.f};
      sf[nt] = __builtin_amdgcn_mfma_f32_16x16x32_bf16(aq, bk, z, 0, 0, 0);
    }
    float mx[4] = {-1e30f, -1e30f, -1e30f, -1e30f};
    #pragma unroll
    for (int nt = 0; nt < 7; ++nt) {
      f32x4 bm = *(const f32x4*)(bmh + (mt * 7 + nt) * 256 + lane * 4);
      #pragma unroll
      for (int r = 0; r < 4; ++r) {
        float s = sf[nt][r] + bm[r];
        sf[nt][r] = s;
        mx[r] = fmaxf(mx[r], s);
      }
    }
    #pragma unroll
    for (int m = 1; m < 16; m <<= 1)
      #pragma unroll
      for (int r = 0; r < 4; ++r) mx[r] = fmaxf(mx[r], __shfl_xor(mx[r], m, 64));
    float sm[4] = {0.f, 0.f, 0.f, 0.f};
    #pragma unroll
    for (int nt = 0; nt < 7; ++nt)
      #pragma unroll
      for (int r = 0; r < 4; ++r) {
        float p = __expf(sf[nt][r] - mx[r]);
        sf[nt][r] = p;
        sm[r] += p;
      }
    #pragma unroll
    for (int m = 1; m < 16; m <<= 1)
      #pragma unroll
      for (int r = 0; r < 4; ++r) sm[r] += __shfl_xor(sm[r], m, 64);
    float inv[4];
    #pragma unroll
    for (int r = 0; r < 4; ++r) inv[r] = 1.0f / sm[r];
    #pragma unroll
    for (int nt = 0; nt < 7; ++nt)
      #pragma unroll
      for (int r = 0; r < 4; ++r)
        P[lhi * 4 + r][nt * 16 + l15] = f2bf(sf[nt][r] * inv[r]);
    f32x4 o0 = {}, o1 = {};
    #pragma unroll
    for (int ks = 0; ks < 4; ++ks) {
      bf16x8 ap  = *(const bf16x8*)(&P[l15][ks * 32 + lhi * 8]);
      bf16x8 bv0 = *(const bf16x8*)(&vT[l15][ks * 32 + lhi * 8]);
      bf16x8 bv1 = *(const bf16x8*)(&vT[16 + l15][ks * 32 + lhi * 8]);
      o0 = __builtin_amdgcn_mfma_f32_16x16x32_bf16(ap, bv0, o0, 0, 0, 0);
      o1 = __builtin_amdgcn_mfma_f32_16x16x32_bf16(ap, bv1, o1, 0, 0, 0);
    }
    int irow0 = mt * 16 + lhi * 4;
    #pragma unroll
    for (int r = 0; r < 4; ++r) {
      if (irow0 + r < 98) {
        size_t orow = obase + (size_t)(irow0 + r) * 128 + h * 32;
        out_win[orow + l15] = f2bf(o0[r]);
        out_win[orow + 16 + l15] = f2bf(o1[r]);
      }
    }
  }
}

// ---------------- launcher ----------------
extern "C" void kernel_launch(void* const* d_in, const int* in_sizes, int n_in,
                              void* d_out, int out_size, void* d_ws, size_t ws_size,
                              hipStream_t stream)
{
  const float* x      = (const float*)d_in[0];
  const float* n1w    = (const float*)d_in[1];
  const float* n1b    = (const float*)d_in[2];
  const float* qkv_w  = (const float*)d_in[3];
  const float* qkv_b  = (const float*)d_in[4];
  const float* rpb    = (const float*)d_in[5];
  const float* proj_w = (const float*)d_in[6];
  const float* proj_b = (const float*)d_in[7];
  const float* n2w    = (const float*)d_in[8];
  const float* n2b    = (const float*)d_in[9];
  const float* fc1_w  = (const float*)d_in[10];
  const float* fc1_b  = (const float*)d_in[11];
  const float* fc2_w  = (const float*)d_in[12];
  const float* fc2_b  = (const float*)d_in[13];

  char* p = (char*)d_ws;
  size_t off = 0;
  auto alloc = [&](size_t bytes) { void* r = p + off; off = (off + bytes + 255) & ~(size_t)255; return r; };
  u16*   qkvw_b    = (u16*)alloc(49152 * 2);
  u16*   projw_b   = (u16*)alloc(16384 * 2);
  u16*   fc1w_b    = (u16*)alloc(65536 * 2);
  u16*   fc2w_b    = (u16*)alloc(65536 * 2);
  float* biasmask  = (float*)alloc(8 * 4 * 49 * 256 * 4);
  u16*   y_win     = (u16*)alloc((size_t)TT * 128 * 2);   // LN1 out, then attn out
  u16*   x2        = (u16*)alloc((size_t)TT * 128 * 2);   // bf16 residual
  u16*   big       = (u16*)alloc((size_t)TT * 384 * 2);   // qkv
  if (off > ws_size) return;

  convert4_kernel<<<768, 256, 0, stream>>>(qkv_w, proj_w, fc1_w, fc2_w,
                                           qkvw_b, projw_b, fc1w_b, fc2w_b);
  biasmask_kernel<<<392, 256, 0, stream>>>(rpb, biasmask);
  ln_kernel<<<TT / 4, 256, 0, stream>>>(x, n1w, n1b, y_win);
  qkvgemm_kernel<<<dim3(TT / 128, 3), 256, 0, stream>>>(y_win, qkvw_b, qkv_b, big);
  attn_kernel<<<BWIN * 4, 64, 0, stream>>>(big, biasmask, y_win);
  proj_kernel<<<TT / 128, 256, 0, stream>>>(y_win, projw_b, proj_b, x, x2);
  mlp_kernel<<<TT / 128, 256, 0, stream>>>(x2, n2w, n2b, fc1w_b, fc1_b, fc2w_b, fc2_b, (float*)d_out);
}